// Round 2
// baseline (1590.736 us; speedup 1.0000x reference)
//
#include <hip/hip_runtime.h>
#include <math.h>

#define CI 64
#define HH 256
#define WW 256
#define SS (HH*WW)

// ---------------- workspace layout (floats) ----------------
// num: [N][1024]  (h*256+k*16+v)  -> 4096
// den: [N][64]    (h*16+k)        -> 256

__global__ void k_zero(float* __restrict__ ws) {
  int i = blockIdx.x * 256 + threadIdx.x;
  if (i < 4352) ws[i] = 0.f;
}

// load 64x64 weight matrix transposed into LDS: wT[c*68+o] = w[o*64+c]
__device__ __forceinline__ void load_wT(const float* __restrict__ w, float* wT, int t) {
#pragma unroll
  for (int i = 0; i < 16; i++) {
    int idx = t + i * 256;     // idx = c*64+o
    int c = idx >> 6, o = idx & 63;
    wT[c * 68 + o] = w[o * 64 + c];
  }
}

// per-thread 16-output GEMM: a[j] += sum_c wT[c][og*16+j] * samp[c][pix]
__device__ __forceinline__ void gemm16(const float* __restrict__ samp,
                                       const float* __restrict__ wT,
                                       int og, int pix, float a[16]) {
#pragma unroll
  for (int j = 0; j < 16; j++) a[j] = 0.f;
  for (int c = 0; c < 64; c++) {
    float sv = samp[c * 64 + pix];
    const float4* wr = reinterpret_cast<const float4*>(wT + c * 68 + og * 16);
    float4 q0 = wr[0], q1 = wr[1], q2 = wr[2], q3 = wr[3];
    a[0] += q0.x * sv;  a[1] += q0.y * sv;  a[2]  += q0.z * sv;  a[3]  += q0.w * sv;
    a[4] += q1.x * sv;  a[5] += q1.y * sv;  a[6]  += q1.z * sv;  a[7]  += q1.w * sv;
    a[8] += q2.x * sv;  a[9] += q2.y * sv;  a[10] += q2.z * sv;  a[11] += q2.w * sv;
    a[12]+= q3.x * sv;  a[13]+= q3.y * sv;  a[14] += q3.z * sv;  a[15] += q3.w * sv;
  }
}

// bilinear sampling params for one pixel: premultiplied tap weights + clamped addresses
__device__ __forceinline__ void bilin_params(float py, float px,
                                             float w[4], int a[4]) {
  float y0f = floorf(py), x0f = floorf(px);
  float wy1 = py - y0f, wy0 = 1.f - wy1;
  float wx1 = px - x0f, wx0 = 1.f - wx1;
  int iy0 = (int)y0f, ix0 = (int)x0f;
  int iy1 = iy0 + 1, ix1 = ix0 + 1;
  float vy0 = (iy0 >= 0 && iy0 < HH) ? 1.f : 0.f;
  float vy1 = (iy1 >= 0 && iy1 < HH) ? 1.f : 0.f;
  float vx0 = (ix0 >= 0 && ix0 < WW) ? 1.f : 0.f;
  float vx1 = (ix1 >= 0 && ix1 < WW) ? 1.f : 0.f;
  int cy0 = min(max(iy0, 0), HH - 1), cy1 = min(max(iy1, 0), HH - 1);
  int cx0 = min(max(ix0, 0), WW - 1), cx1 = min(max(ix1, 0), WW - 1);
  w[0] = wy0 * wx0 * vy0 * vx0;
  w[1] = wy0 * wx1 * vy0 * vx1;
  w[2] = wy1 * wx0 * vy1 * vx0;
  w[3] = wy1 * wx1 * vy1 * vx1;
  a[0] = cy0 * WW + cx0;  a[1] = cy0 * WW + cx1;
  a[2] = cy1 * WW + cx0;  a[3] = cy1 * WW + cx1;
}

// ---------------- K1: context accumulation ----------------
__global__ __launch_bounds__(256) void k_context(
    const float* __restrict__ x,
    const float* __restrict__ kow, const float* __restrict__ kob,
    const float* __restrict__ kw,
    const float* __restrict__ vow, const float* __restrict__ vob,
    const float* __restrict__ vw,
    float* __restrict__ num, float* __restrict__ den) {
  __shared__ float wT[64 * 68];
  __shared__ float samp[64 * 64];
  __shared__ float ekt[64 * 68];
  __shared__ float vlt[64 * 68];
  __shared__ float red[16 * 64];
  __shared__ float pws[2][4][64];
  __shared__ int   pas[2][4][64];

  const int t = threadIdx.x;
  const int b = blockIdx.x;
  const int n = b >> 8;
  const int yrow = b & 255;
  const float* xn = x + (size_t)n * CI * SS;
  const int pix = t & 63;
  const int cg = t >> 6;

  float acc[4] = {0.f, 0.f, 0.f, 0.f};
  float dacc = 0.f;

  for (int it = 0; it < 4; ++it) {
    const int xb = it * 64;
    const int s0 = yrow * WW + xb;

    // ---- A: offset partial dots (k and v) + stage kw ----
    {
      float p0 = 0, p1 = 0, p2 = 0, p3 = 0;
      const float* xc = xn + (size_t)(cg * 16) * SS + s0 + pix;
#pragma unroll
      for (int i = 0; i < 16; i++) {
        float xv = xc[(size_t)i * SS];
        int c = cg * 16 + i;
        p0 += kow[c] * xv;  p1 += kow[64 + c] * xv;
        p2 += vow[c] * xv;  p3 += vow[64 + c] * xv;
      }
      red[(0 * 4 + cg) * 64 + pix] = p0;
      red[(1 * 4 + cg) * 64 + pix] = p1;
      red[(2 * 4 + cg) * 64 + pix] = p2;
      red[(3 * 4 + cg) * 64 + pix] = p3;
      load_wT(kw, wT, t);
    }
    __syncthreads();
    // ---- A2: per-pixel bilinear params for k (sel=0) and v (sel=1) ----
    if (t < 128) {
      int p = t & 63, sel = t >> 6, qb = sel * 2;
      float oy = red[((qb + 0) * 4 + 0) * 64 + p] + red[((qb + 0) * 4 + 1) * 64 + p] +
                 red[((qb + 0) * 4 + 2) * 64 + p] + red[((qb + 0) * 4 + 3) * 64 + p];
      float ox = red[((qb + 1) * 4 + 0) * 64 + p] + red[((qb + 1) * 4 + 1) * 64 + p] +
                 red[((qb + 1) * 4 + 2) * 64 + p] + red[((qb + 1) * 4 + 3) * 64 + p];
      const float* ob = sel ? vob : kob;
      float py = (float)yrow + oy + ob[0];
      float px = (float)(xb + p) + ox + ob[1];
      float w4[4]; int a4[4];
      bilin_params(py, px, w4, a4);
#pragma unroll
      for (int q = 0; q < 4; q++) { pws[sel][q][p] = w4[q]; pas[sel][q][p] = a4[q]; }
    }
    __syncthreads();
    // ---- C: sample k -> samp ----
    {
      float w0 = pws[0][0][pix], w1 = pws[0][1][pix], w2 = pws[0][2][pix], w3 = pws[0][3][pix];
      int a0 = pas[0][0][pix], a1 = pas[0][1][pix], a2 = pas[0][2][pix], a3 = pas[0][3][pix];
#pragma unroll
      for (int i = 0; i < 16; i++) {
        const float* Xc = xn + (size_t)(cg * 16 + i) * SS;
        samp[(cg * 16 + i) * 64 + pix] = w0 * Xc[a0] + w1 * Xc[a1] + w2 * Xc[a2] + w3 * Xc[a3];
      }
    }
    __syncthreads();
    // ---- D: keys GEMM + exp -> ekt ----
    {
      float a[16];
      gemm16(samp, wT, cg, pix, a);
#pragma unroll
      for (int j = 0; j < 16; j++) ekt[(cg * 16 + j) * 68 + pix] = expf(a[j]);
    }
    __syncthreads();
    // ---- E: stage vw + sample v -> samp ----
    {
      load_wT(vw, wT, t);
      float w0 = pws[1][0][pix], w1 = pws[1][1][pix], w2 = pws[1][2][pix], w3 = pws[1][3][pix];
      int a0 = pas[1][0][pix], a1 = pas[1][1][pix], a2 = pas[1][2][pix], a3 = pas[1][3][pix];
#pragma unroll
      for (int i = 0; i < 16; i++) {
        const float* Xc = xn + (size_t)(cg * 16 + i) * SS;
        samp[(cg * 16 + i) * 64 + pix] = w0 * Xc[a0] + w1 * Xc[a1] + w2 * Xc[a2] + w3 * Xc[a3];
      }
    }
    __syncthreads();
    // ---- F: values GEMM -> vlt ----
    {
      float a[16];
      gemm16(samp, wT, cg, pix, a);
#pragma unroll
      for (int j = 0; j < 16; j++) vlt[(cg * 16 + j) * 68 + pix] = a[j];
    }
    __syncthreads();
    // ---- G: accumulate context num (4 entries/thread, float4 + 4 chains) ----
    {
#pragma unroll
      for (int j = 0; j < 4; j++) {
        int e = t + j * 256;                           // e = h*256 + k*16 + v
        int hrow = ((e >> 8) << 4) + ((e >> 4) & 15);  // h*16+k
        int vrow = ((e >> 8) << 4) + (e & 15);         // h*16+v
        const float4* er = reinterpret_cast<const float4*>(&ekt[hrow * 68]);
        const float4* vr = reinterpret_cast<const float4*>(&vlt[vrow * 68]);
        float s0 = 0.f, s1 = 0.f, s2 = 0.f, s3 = 0.f;
#pragma unroll
        for (int p = 0; p < 16; p++) {
          float4 ev = er[p], vv = vr[p];
          s0 += ev.x * vv.x; s1 += ev.y * vv.y;
          s2 += ev.z * vv.z; s3 += ev.w * vv.w;
        }
        acc[j] += (s0 + s1) + (s2 + s3);
      }
      if (t < 64) {
        const float4* er = reinterpret_cast<const float4*>(&ekt[t * 68]);
        float s0 = 0.f, s1 = 0.f, s2 = 0.f, s3 = 0.f;
#pragma unroll
        for (int p = 0; p < 16; p++) {
          float4 ev = er[p];
          s0 += ev.x; s1 += ev.y; s2 += ev.z; s3 += ev.w;
        }
        dacc += (s0 + s1) + (s2 + s3);
      }
    }
    __syncthreads();
  }
#pragma unroll
  for (int j = 0; j < 4; j++) atomicAdd(&num[n * 1024 + t + j * 256], acc[j]);
  if (t < 64) atomicAdd(&den[n * 64 + t], dacc);
}

// ---------------- K3: query path + output (ctx normalize fused) ----------------
__global__ __launch_bounds__(256) void k_output(
    const float* __restrict__ x,
    const float* __restrict__ qow, const float* __restrict__ qob,
    const float* __restrict__ qw,
    const float* __restrict__ rw, const float* __restrict__ rb,
    const float* __restrict__ num, const float* __restrict__ den,
    float* __restrict__ out) {
  __shared__ float wT[64 * 68];
  __shared__ float samp[64 * 64];   // sampled q, later attended tile
  __shared__ float qt[64 * 64];     // queries, then q-softmax
  __shared__ float red[8 * 64];
  __shared__ float pws[4][64];
  __shared__ int   pas[4][64];
  __shared__ float ctxs[1024];

  const int t = threadIdx.x;
  const int b = blockIdx.x;
  const int n = b >> 8;
  const int yrow = b & 255;
  const float* xn = x + (size_t)n * CI * SS;
  const int pix = t & 63;
  const int cg = t >> 6;

#pragma unroll
  for (int i = 0; i < 4; i++) {
    int e = t + i * 256;
    ctxs[e] = num[n * 1024 + e] / den[n * 64 + (e >> 4)];
  }
  __syncthreads();

  for (int it = 0; it < 4; ++it) {
    const int xb = it * 64;
    const int s0 = yrow * WW + xb;

    // ---- A: q offset partial dots + stage qw ----
    {
      float p0 = 0, p1 = 0;
      const float* xc = xn + (size_t)(cg * 16) * SS + s0 + pix;
#pragma unroll
      for (int i = 0; i < 16; i++) {
        float xv = xc[(size_t)i * SS];
        int c = cg * 16 + i;
        p0 += qow[c] * xv;  p1 += qow[64 + c] * xv;
      }
      red[(0 * 4 + cg) * 64 + pix] = p0;
      red[(1 * 4 + cg) * 64 + pix] = p1;
      load_wT(qw, wT, t);
    }
    __syncthreads();
    if (t < 64) {
      float oy = red[0 * 64 + t] + red[1 * 64 + t] + red[2 * 64 + t] + red[3 * 64 + t];
      float ox = red[4 * 64 + t] + red[5 * 64 + t] + red[6 * 64 + t] + red[7 * 64 + t];
      float py = (float)yrow + oy + qob[0];
      float px = (float)(xb + t) + ox + qob[1];
      float w4[4]; int a4[4];
      bilin_params(py, px, w4, a4);
#pragma unroll
      for (int q = 0; q < 4; q++) { pws[q][t] = w4[q]; pas[q][t] = a4[q]; }
    }
    __syncthreads();
    // ---- C: sample q ----
    {
      float w0 = pws[0][pix], w1 = pws[1][pix], w2 = pws[2][pix], w3 = pws[3][pix];
      int a0 = pas[0][pix], a1 = pas[1][pix], a2 = pas[2][pix], a3 = pas[3][pix];
#pragma unroll
      for (int i = 0; i < 16; i++) {
        const float* Xc = xn + (size_t)(cg * 16 + i) * SS;
        samp[(cg * 16 + i) * 64 + pix] = w0 * Xc[a0] + w1 * Xc[a1] + w2 * Xc[a2] + w3 * Xc[a3];
      }
    }
    __syncthreads();
    // ---- D: queries GEMM -> qt ----
    {
      float a[16];
      gemm16(samp, wT, cg, pix, a);
#pragma unroll
      for (int j = 0; j < 16; j++) qt[(cg * 16 + j) * 64 + pix] = a[j];
    }
    __syncthreads();
    // ---- D2: per-pixel per-head softmax over dk=16 (thread = (pix, h=cg)) ----
    {
      float v[16];
#pragma unroll
      for (int k = 0; k < 16; k++) v[k] = qt[(cg * 16 + k) * 64 + pix];
      float m = v[0];
#pragma unroll
      for (int k = 1; k < 16; k++) m = fmaxf(m, v[k]);
      float ssum = 0.f;
#pragma unroll
      for (int k = 0; k < 16; k++) { v[k] = expf(v[k] - m); ssum += v[k]; }
      float inv = 1.f / ssum;
#pragma unroll
      for (int k = 0; k < 16; k++) qt[(cg * 16 + k) * 64 + pix] = v[k] * inv;
    }
    __syncthreads();
    // ---- E: attended tile -> samp (overwrite), stage rp_w ----
    {
      load_wT(rw, wT, t);
#pragma unroll
      for (int j = 0; j < 16; j++) {
        int r = cg * 16 + j;         // r = h*16 + v (aggregated channel)
        int h = r >> 4, vv = r & 15;
        float a = 0.f;
#pragma unroll
        for (int k = 0; k < 16; k++)
          a += ctxs[h * 256 + k * 16 + vv] * qt[(h * 16 + k) * 64 + pix];
        samp[r * 64 + pix] = a;
      }
    }
    __syncthreads();
    // ---- F: output GEMM + bias, store ----
    {
      float a[16];
      gemm16(samp, wT, cg, pix, a);
#pragma unroll
      for (int j = 0; j < 16; j++) {
        int o = cg * 16 + j;
        out[(size_t)(n * 64 + o) * SS + s0 + pix] = a[j] + rb[o];
      }
    }
    __syncthreads();
  }
}

extern "C" void kernel_launch(void* const* d_in, const int* in_sizes, int n_in,
                              void* d_out, int out_size, void* d_ws, size_t ws_size,
                              hipStream_t stream) {
  const float* x   = (const float*)d_in[0];
  const float* kow = (const float*)d_in[1];
  const float* kob = (const float*)d_in[2];
  const float* kw  = (const float*)d_in[3];
  const float* qow = (const float*)d_in[4];
  const float* qob = (const float*)d_in[5];
  const float* qw  = (const float*)d_in[6];
  const float* vow = (const float*)d_in[7];
  const float* vob = (const float*)d_in[8];
  const float* vw  = (const float*)d_in[9];
  const float* rw  = (const float*)d_in[10];
  const float* rb  = (const float*)d_in[11];
  float* out = (float*)d_out;
  float* wsf = (float*)d_ws;
  float* num = wsf;          // 4096
  float* den = wsf + 4096;   // 256

  hipLaunchKernelGGL(k_zero, dim3(17), dim3(256), 0, stream, wsf);
  hipLaunchKernelGGL(k_context, dim3(1024), dim3(256), 0, stream,
                     x, kow, kob, kw, vow, vob, vw, num, den);
  hipLaunchKernelGGL(k_output, dim3(1024), dim3(256), 0, stream,
                     x, qow, qob, qw, rw, rb, num, den, out);
}

// Round 3
// 484.750 us; speedup vs baseline: 3.2816x; 3.2816x over previous
//
#include <hip/hip_runtime.h>
#include <math.h>

#define CI 64
#define HH 256
#define WW 256
#define SS (HH*WW)

// workspace: num [N][1024] (h*256+k*16+v) -> 4096 ; den [N][64] -> 256

__global__ void k_zero(float* __restrict__ ws) {
  int i = blockIdx.x * 256 + threadIdx.x;
  if (i < 4352) ws[i] = 0.f;
}

__device__ __forceinline__ void bilin_params(float py, float px, float w[4], int a[4]) {
  float y0f = floorf(py), x0f = floorf(px);
  float wy1 = py - y0f, wy0 = 1.f - wy1;
  float wx1 = px - x0f, wx0 = 1.f - wx1;
  int iy0 = (int)y0f, ix0 = (int)x0f;
  int iy1 = iy0 + 1, ix1 = ix0 + 1;
  float vy0 = (iy0 >= 0 && iy0 < HH) ? 1.f : 0.f;
  float vy1 = (iy1 >= 0 && iy1 < HH) ? 1.f : 0.f;
  float vx0 = (ix0 >= 0 && ix0 < WW) ? 1.f : 0.f;
  float vx1 = (ix1 >= 0 && ix1 < WW) ? 1.f : 0.f;
  int cy0 = min(max(iy0, 0), HH - 1), cy1 = min(max(iy1, 0), HH - 1);
  int cx0 = min(max(ix0, 0), WW - 1), cx1 = min(max(ix1, 0), WW - 1);
  w[0] = wy0 * wx0 * vy0 * vx0;
  w[1] = wy0 * wx1 * vy0 * vx1;
  w[2] = wy1 * wx0 * vy1 * vx0;
  w[3] = wy1 * wx1 * vy1 * vx1;
  a[0] = cy0 * WW + cx0;  a[1] = cy0 * WW + cx1;
  a[2] = cy1 * WW + cx0;  a[3] = cy1 * WW + cx1;
}

// 16-output per-thread GEMM. samp row [pix*64] XOR-chunk-swizzled; weights via
// wave-uniform scalar loads (wblk formed from readfirstlane'd index).
__device__ __forceinline__ void gemm16s(const float* __restrict__ sp,
                                        const float* __restrict__ wblk,
                                        int p7, float a[16]) {
#pragma unroll
  for (int j = 0; j < 16; j++) a[j] = 0.f;
#pragma unroll 2
  for (int m = 0; m < 16; m++) {
    float4 sv = *reinterpret_cast<const float4*>(sp + ((m ^ p7) << 2));
#pragma unroll
    for (int j = 0; j < 16; j++) {
      const float* wr = wblk + j * 64 + m * 4;
      a[j] += wr[0] * sv.x + wr[1] * sv.y + wr[2] * sv.z + wr[3] * sv.w;
    }
  }
}

// sample 16 channels (cg*16..+15) for this thread's pixel -> swizzled float4 writes
__device__ __forceinline__ void sample16(const float* __restrict__ Xb,
                                         const float* __restrict__ pw,
                                         const int* __restrict__ pa,
                                         float* __restrict__ samp,
                                         int pix, int cg, int p7) {
  float w0 = pw[0 * 64 + pix], w1 = pw[1 * 64 + pix], w2 = pw[2 * 64 + pix], w3 = pw[3 * 64 + pix];
  int a0 = pa[0 * 64 + pix], a1 = pa[1 * 64 + pix], a2 = pa[2 * 64 + pix], a3 = pa[3 * 64 + pix];
#pragma unroll 2
  for (int mc = 0; mc < 4; mc++) {
    float vv[4];
#pragma unroll
    for (int q = 0; q < 4; q++) {
      const float* Xc = Xb + (size_t)(mc * 4 + q) * SS;
      vv[q] = w0 * Xc[a0] + w1 * Xc[a1] + w2 * Xc[a2] + w3 * Xc[a3];
    }
    *reinterpret_cast<float4*>(&samp[pix * 64 + (((cg * 4 + mc) ^ p7) << 2)]) =
        make_float4(vv[0], vv[1], vv[2], vv[3]);
  }
}

// ---------------- K1: context accumulation (one 64-px tile per block) ----------------
__global__ __launch_bounds__(256, 3) void k_context(
    const float* __restrict__ x,
    const float* __restrict__ kow, const float* __restrict__ kob,
    const float* __restrict__ kw,
    const float* __restrict__ vow, const float* __restrict__ vob,
    const float* __restrict__ vw,
    float* __restrict__ num, float* __restrict__ den) {
  __shared__ float ekt[64 * 68];
  __shared__ float vlt[64 * 68];
  __shared__ float samp[64 * 64];
  float* red = ekt;                 // [4][4][64], dead before D writes ekt
  float* pws = vlt;                 // [2][4][64], dead before F writes vlt
  int*   pas = (int*)(vlt + 512);   // [2][4][64]

  const int t = threadIdx.x;
  const int b = blockIdx.x;
  const int xt = b & 3, yrow = (b >> 2) & 255, n = b >> 10;
  const int xb = xt * 64;
  const int s0 = yrow * WW + xb;
  const float* xn = x + (size_t)n * CI * SS;
  const int pix = t & 63;
  const int cg = t >> 6;
  const int cgu = __builtin_amdgcn_readfirstlane(cg);
  const int p7 = pix & 7;
  const float* Xb = xn + (size_t)(cgu * 16) * SS;

  // A: offset partial dots (k and v), weights scalar
  {
    const float* xc = Xb + s0 + pix;
    float p0 = 0, p1 = 0, p2 = 0, p3 = 0;
#pragma unroll 8
    for (int i = 0; i < 16; i++) {
      float xv = xc[(size_t)i * SS];
      p0 += kow[cgu * 16 + i] * xv;
      p1 += kow[64 + cgu * 16 + i] * xv;
      p2 += vow[cgu * 16 + i] * xv;
      p3 += vow[64 + cgu * 16 + i] * xv;
    }
    red[(0 * 4 + cg) * 64 + pix] = p0;
    red[(1 * 4 + cg) * 64 + pix] = p1;
    red[(2 * 4 + cg) * 64 + pix] = p2;
    red[(3 * 4 + cg) * 64 + pix] = p3;
  }
  __syncthreads();
  // A2: bilinear params (sel 0=k, 1=v)
  if (t < 128) {
    int p = t & 63, sel = t >> 6, qb = sel * 2;
    float oy = red[((qb + 0) * 4 + 0) * 64 + p] + red[((qb + 0) * 4 + 1) * 64 + p] +
               red[((qb + 0) * 4 + 2) * 64 + p] + red[((qb + 0) * 4 + 3) * 64 + p];
    float ox = red[((qb + 1) * 4 + 0) * 64 + p] + red[((qb + 1) * 4 + 1) * 64 + p] +
               red[((qb + 1) * 4 + 2) * 64 + p] + red[((qb + 1) * 4 + 3) * 64 + p];
    const float* ob = sel ? vob : kob;
    float py = (float)yrow + oy + ob[0];
    float px = (float)(xb + p) + ox + ob[1];
    float w4[4]; int a4[4];
    bilin_params(py, px, w4, a4);
#pragma unroll
    for (int q = 0; q < 4; q++) { pws[(sel * 4 + q) * 64 + p] = w4[q]; pas[(sel * 4 + q) * 64 + p] = a4[q]; }
  }
  __syncthreads();
  // C: sample k
  sample16(Xb, pws, pas, samp, pix, cg, p7);
  __syncthreads();
  // D: keys GEMM + exp -> ekt (clobbers red: consumed)
  {
    float a[16];
    gemm16s(&samp[pix * 64], kw + (size_t)cgu * 16 * 64, p7, a);
#pragma unroll
    for (int j = 0; j < 16; j++) ekt[(cg * 16 + j) * 68 + pix] = __expf(a[j]);
  }
  __syncthreads();
  // E: sample v
  sample16(Xb, pws + 4 * 64, pas + 4 * 64, samp, pix, cg, p7);
  __syncthreads();
  // F: values GEMM -> vlt (clobbers pws/pas: consumed)
  {
    float a[16];
    gemm16s(&samp[pix * 64], vw + (size_t)cgu * 16 * 64, p7, a);
#pragma unroll
    for (int j = 0; j < 16; j++) vlt[(cg * 16 + j) * 68 + pix] = a[j];
  }
  __syncthreads();
  // G: context outer-product accumulate + denom, then atomics
  float acc[4]; float dacc = 0.f;
#pragma unroll
  for (int j = 0; j < 4; j++) {
    int e = t + j * 256;
    int hrow = ((e >> 8) << 4) + ((e >> 4) & 15);
    int vrow = ((e >> 8) << 4) + (e & 15);
    const float4* er = (const float4*)&ekt[hrow * 68];
    const float4* vr = (const float4*)&vlt[vrow * 68];
    float s0_ = 0, s1_ = 0, s2_ = 0, s3_ = 0;
#pragma unroll 4
    for (int p = 0; p < 16; p++) {
      float4 ev = er[p], vv = vr[p];
      s0_ += ev.x * vv.x; s1_ += ev.y * vv.y; s2_ += ev.z * vv.z; s3_ += ev.w * vv.w;
    }
    acc[j] = (s0_ + s1_) + (s2_ + s3_);
  }
  if (t < 64) {
    const float4* er = (const float4*)&ekt[t * 68];
    float s0_ = 0, s1_ = 0, s2_ = 0, s3_ = 0;
#pragma unroll 4
    for (int p = 0; p < 16; p++) { float4 ev = er[p]; s0_ += ev.x; s1_ += ev.y; s2_ += ev.z; s3_ += ev.w; }
    dacc = (s0_ + s1_) + (s2_ + s3_);
  }
#pragma unroll
  for (int j = 0; j < 4; j++) atomicAdd(&num[n * 1024 + t + j * 256], acc[j]);
  if (t < 64) atomicAdd(&den[n * 64 + t], dacc);
}

// ---------------- K3: query path + output (one tile per block) ----------------
__global__ __launch_bounds__(256, 4) void k_output(
    const float* __restrict__ x,
    const float* __restrict__ qow, const float* __restrict__ qob,
    const float* __restrict__ qw,
    const float* __restrict__ rw, const float* __restrict__ rb,
    const float* __restrict__ num, const float* __restrict__ den,
    float* __restrict__ out) {
  __shared__ float samp[64 * 64];
  __shared__ float qt[64 * 64];
  __shared__ float ctxs[1024];
  float* red2 = qt;                 // [2][4][64] = 512, dead before D writes qt
  float* pws2 = qt + 512;           // [4][64]
  int*   pas2 = (int*)(qt + 768);   // [4][64]

  const int t = threadIdx.x;
  const int b = blockIdx.x;
  const int xt = b & 3, yrow = (b >> 2) & 255, n = b >> 10;
  const int xb = xt * 64;
  const int s0 = yrow * WW + xb;
  const float* xn = x + (size_t)n * CI * SS;
  const int pix = t & 63;
  const int cg = t >> 6;
  const int cgu = __builtin_amdgcn_readfirstlane(cg);
  const int p7 = pix & 7;
  const float* Xb = xn + (size_t)(cgu * 16) * SS;

  // ctx normalize (read in E; ordered by the A barrier)
#pragma unroll
  for (int i = 0; i < 4; i++) {
    int e = t + i * 256;
    ctxs[e] = num[n * 1024 + e] / den[n * 64 + (e >> 4)];
  }

  // A: q offset partial dots
  {
    const float* xc = Xb + s0 + pix;
    float p0 = 0, p1 = 0;
#pragma unroll 8
    for (int i = 0; i < 16; i++) {
      float xv = xc[(size_t)i * SS];
      p0 += qow[cgu * 16 + i] * xv;
      p1 += qow[64 + cgu * 16 + i] * xv;
    }
    red2[(0 * 4 + cg) * 64 + pix] = p0;
    red2[(1 * 4 + cg) * 64 + pix] = p1;
  }
  __syncthreads();
  // A2
  if (t < 64) {
    float oy = red2[0 * 64 + t] + red2[1 * 64 + t] + red2[2 * 64 + t] + red2[3 * 64 + t];
    float ox = red2[4 * 64 + t] + red2[5 * 64 + t] + red2[6 * 64 + t] + red2[7 * 64 + t];
    float py = (float)yrow + oy + qob[0];
    float px = (float)(xb + t) + ox + qob[1];
    float w4[4]; int a4[4];
    bilin_params(py, px, w4, a4);
#pragma unroll
    for (int q = 0; q < 4; q++) { pws2[q * 64 + t] = w4[q]; pas2[q * 64 + t] = a4[q]; }
  }
  __syncthreads();
  // C: sample q
  sample16(Xb, pws2, pas2, samp, pix, cg, p7);
  __syncthreads();
  // D: queries GEMM -> qt (clobbers red2/pws2/pas2: consumed)
  {
    float a[16];
    gemm16s(&samp[pix * 64], qw + (size_t)cgu * 16 * 64, p7, a);
#pragma unroll
    for (int j = 0; j < 16; j++) qt[(cg * 16 + j) * 64 + pix] = a[j];
  }
  __syncthreads();
  // D2: per-pixel per-head softmax over dk=16
  {
    float v[16];
#pragma unroll
    for (int k = 0; k < 16; k++) v[k] = qt[(cg * 16 + k) * 64 + pix];
    float m = v[0];
#pragma unroll
    for (int k = 1; k < 16; k++) m = fmaxf(m, v[k]);
    float ssum = 0.f;
#pragma unroll
    for (int k = 0; k < 16; k++) { v[k] = __expf(v[k] - m); ssum += v[k]; }
    float inv = 1.f / ssum;
#pragma unroll
    for (int k = 0; k < 16; k++) qt[(cg * 16 + k) * 64 + pix] = v[k] * inv;
  }
  __syncthreads();
  // E: attended -> samp (h = cg uniform; ctxs broadcast reads)
  {
    float a[16];
#pragma unroll
    for (int j = 0; j < 16; j++) a[j] = 0.f;
    const float* cb = ctxs + cg * 256;
#pragma unroll 4
    for (int k = 0; k < 16; k++) {
      float qv = qt[(cg * 16 + k) * 64 + pix];
#pragma unroll
      for (int j = 0; j < 16; j++) a[j] += cb[k * 16 + j] * qv;
    }
#pragma unroll
    for (int mc = 0; mc < 4; mc++) {
      *reinterpret_cast<float4*>(&samp[pix * 64 + (((cg * 4 + mc) ^ p7) << 2)]) =
          make_float4(a[mc * 4], a[mc * 4 + 1], a[mc * 4 + 2], a[mc * 4 + 3]);
    }
  }
  __syncthreads();
  // F: output GEMM + bias, store
  {
    float a[16];
    gemm16s(&samp[pix * 64], rw + (size_t)cgu * 16 * 64, p7, a);
#pragma unroll
    for (int j = 0; j < 16; j++) {
      int o = cgu * 16 + j;
      out[(size_t)(n * 64 + o) * SS + s0 + pix] = a[j] + rb[o];
    }
  }
}

extern "C" void kernel_launch(void* const* d_in, const int* in_sizes, int n_in,
                              void* d_out, int out_size, void* d_ws, size_t ws_size,
                              hipStream_t stream) {
  const float* x   = (const float*)d_in[0];
  const float* kow = (const float*)d_in[1];
  const float* kob = (const float*)d_in[2];
  const float* kw  = (const float*)d_in[3];
  const float* qow = (const float*)d_in[4];
  const float* qob = (const float*)d_in[5];
  const float* qw  = (const float*)d_in[6];
  const float* vow = (const float*)d_in[7];
  const float* vob = (const float*)d_in[8];
  const float* vw  = (const float*)d_in[9];
  const float* rw  = (const float*)d_in[10];
  const float* rb  = (const float*)d_in[11];
  float* out = (float*)d_out;
  float* wsf = (float*)d_ws;
  float* num = wsf;          // 4096
  float* den = wsf + 4096;   // 256

  hipLaunchKernelGGL(k_zero, dim3(17), dim3(256), 0, stream, wsf);
  hipLaunchKernelGGL(k_context, dim3(4096), dim3(256), 0, stream,
                     x, kow, kob, kw, vow, vob, vw, num, den);
  hipLaunchKernelGGL(k_output, dim3(4096), dim3(256), 0, stream,
                     x, qow, qob, qw, rw, rb, num, den, out);
}

// Round 4
// 449.513 us; speedup vs baseline: 3.5388x; 1.0784x over previous
//
#include <hip/hip_runtime.h>
#include <math.h>

#define CI 64
#define HH 256
#define WW 256
#define SS (HH*WW)

// workspace: num [N][1024] (h*256+k*16+v) -> 4096 ; den [N][64] -> 256

__global__ void k_zero(float* __restrict__ ws) {
  int i = blockIdx.x * 256 + threadIdx.x;
  if (i < 4352) ws[i] = 0.f;
}

// dword index of 4-float chunk `c` in XOR-swizzled row `row` (64 floats/row)
__device__ __forceinline__ int swq(int row, int c) {
  return row * 64 + (((c) ^ (row & 7)) << 2);
}

__device__ __forceinline__ void bilin_params(float py, float px, float w[4], int a[4]) {
  float y0f = floorf(py), x0f = floorf(px);
  float wy1 = py - y0f, wy0 = 1.f - wy1;
  float wx1 = px - x0f, wx0 = 1.f - wx1;
  int iy0 = (int)y0f, ix0 = (int)x0f;
  int iy1 = iy0 + 1, ix1 = ix0 + 1;
  float vy0 = (iy0 >= 0 && iy0 < HH) ? 1.f : 0.f;
  float vy1 = (iy1 >= 0 && iy1 < HH) ? 1.f : 0.f;
  float vx0 = (ix0 >= 0 && ix0 < WW) ? 1.f : 0.f;
  float vx1 = (ix1 >= 0 && ix1 < WW) ? 1.f : 0.f;
  int cy0 = min(max(iy0, 0), HH - 1), cy1 = min(max(iy1, 0), HH - 1);
  int cx0 = min(max(ix0, 0), WW - 1), cx1 = min(max(ix1, 0), WW - 1);
  w[0] = wy0 * wx0 * vy0 * vx0;
  w[1] = wy0 * wx1 * vy0 * vx1;
  w[2] = wy1 * wx0 * vy1 * vx0;
  w[3] = wy1 * wx1 * vy1 * vx1;
  a[0] = cy0 * WW + cx0;  a[1] = cy0 * WW + cx1;
  a[2] = cy1 * WW + cx0;  a[3] = cy1 * WW + cx1;
}

// 16-output per-thread GEMM; samp row XOR-chunk-swizzled; weights wave-uniform scalar loads
__device__ __forceinline__ void gemm16s(const float* __restrict__ sp,
                                        const float* __restrict__ wblk,
                                        int p7, float a[16]) {
#pragma unroll
  for (int j = 0; j < 16; j++) a[j] = 0.f;
#pragma unroll 2
  for (int m = 0; m < 16; m++) {
    float4 sv = *reinterpret_cast<const float4*>(sp + ((m ^ p7) << 2));
#pragma unroll
    for (int j = 0; j < 16; j++) {
      const float* wr = wblk + j * 64 + m * 4;
      a[j] += wr[0] * sv.x + wr[1] * sv.y + wr[2] * sv.z + wr[3] * sv.w;
    }
  }
}

// sample 16 channels (cg*16..+15) for this thread's pixel -> swizzled float4 writes
__device__ __forceinline__ void sample16(const float* __restrict__ Xb,
                                         const float* __restrict__ pw,
                                         const int* __restrict__ pa,
                                         float* __restrict__ samp,
                                         int pix, int cg, int p7) {
  float w0 = pw[0 * 64 + pix], w1 = pw[1 * 64 + pix], w2 = pw[2 * 64 + pix], w3 = pw[3 * 64 + pix];
  int a0 = pa[0 * 64 + pix], a1 = pa[1 * 64 + pix], a2 = pa[2 * 64 + pix], a3 = pa[3 * 64 + pix];
#pragma unroll 2
  for (int mc = 0; mc < 4; mc++) {
    float vv[4];
#pragma unroll
    for (int q = 0; q < 4; q++) {
      const float* Xc = Xb + (size_t)(mc * 4 + q) * SS;
      vv[q] = w0 * Xc[a0] + w1 * Xc[a1] + w2 * Xc[a2] + w3 * Xc[a3];
    }
    *reinterpret_cast<float4*>(&samp[swq(pix, cg * 4 + mc)]) =
        make_float4(vv[0], vv[1], vv[2], vv[3]);
  }
}

// ---------------- K1: context accumulation (one 64-px tile per block, 32KB LDS) ----------------
__global__ __launch_bounds__(256, 4) void k_context(
    const float* __restrict__ x,
    const float* __restrict__ kow, const float* __restrict__ kob,
    const float* __restrict__ kw,
    const float* __restrict__ vow, const float* __restrict__ vob,
    const float* __restrict__ vw,
    float* __restrict__ num, float* __restrict__ den) {
  __shared__ float samp[4096];   // sampled tile (pix-major swz), later vlt (ch-major swz)
  __shared__ float ekt[4096];    // exp(keys) ch-major swz; [0..2047] aliased early:
  float* pws = ekt;              //   [2][4][64] bilinear weights   (0..511)
  int*   pas = (int*)(ekt + 512);//   [2][4][64] tap addrs          (512..1023)
  float* red = ekt + 1024;       //   [4][4][64] offset partials    (1024..2047)
  // all aliased uses end before F2 writes ekt.

  const int t = threadIdx.x;
  const int bp = ((blockIdx.x & 7) << 9) | (blockIdx.x >> 3);  // XCD-chunked remap
  const int xt = bp & 3, yrow = (bp >> 2) & 255, n = bp >> 10;
  const int xb = xt * 64;
  const int s0 = yrow * WW + xb;
  const float* xn = x + (size_t)n * CI * SS;
  const int pix = t & 63;
  const int cg = t >> 6;         // wave id = head id
  const int cgu = __builtin_amdgcn_readfirstlane(cg);
  const int p7 = pix & 7;
  const float* Xb = xn + (size_t)(cgu * 16) * SS;

  // A: offset partial dots (k and v)
  {
    const float* xc = Xb + s0 + pix;
    float p0 = 0, p1 = 0, p2 = 0, p3 = 0;
#pragma unroll 8
    for (int i = 0; i < 16; i++) {
      float xv = xc[(size_t)i * SS];
      p0 += kow[cgu * 16 + i] * xv;
      p1 += kow[64 + cgu * 16 + i] * xv;
      p2 += vow[cgu * 16 + i] * xv;
      p3 += vow[64 + cgu * 16 + i] * xv;
    }
    red[(0 * 4 + cg) * 64 + pix] = p0;
    red[(1 * 4 + cg) * 64 + pix] = p1;
    red[(2 * 4 + cg) * 64 + pix] = p2;
    red[(3 * 4 + cg) * 64 + pix] = p3;
  }
  __syncthreads();
  // A2: bilinear params (sel 0=k, 1=v); red -> pws/pas (disjoint LDS regions)
  if (t < 128) {
    int p = t & 63, sel = t >> 6, qb = sel * 2;
    float oy = red[((qb + 0) * 4 + 0) * 64 + p] + red[((qb + 0) * 4 + 1) * 64 + p] +
               red[((qb + 0) * 4 + 2) * 64 + p] + red[((qb + 0) * 4 + 3) * 64 + p];
    float ox = red[((qb + 1) * 4 + 0) * 64 + p] + red[((qb + 1) * 4 + 1) * 64 + p] +
               red[((qb + 1) * 4 + 2) * 64 + p] + red[((qb + 1) * 4 + 3) * 64 + p];
    const float* ob = sel ? vob : kob;
    float py = (float)yrow + oy + ob[0];
    float px = (float)(xb + p) + ox + ob[1];
    float w4[4]; int a4[4];
    bilin_params(py, px, w4, a4);
#pragma unroll
    for (int q = 0; q < 4; q++) { pws[(sel * 4 + q) * 64 + p] = w4[q]; pas[(sel * 4 + q) * 64 + p] = a4[q]; }
  }
  __syncthreads();
  // C: sample k -> samp
  sample16(Xb, pws, pas, samp, pix, cg, p7);
  __syncthreads();
  // D: keys GEMM -> ek regs + exp (no LDS write yet)
  float ek[16];
  gemm16s(&samp[pix * 64], kw + (size_t)cgu * 16 * 64, p7, ek);
#pragma unroll
  for (int j = 0; j < 16; j++) ek[j] = __expf(ek[j]);
  __syncthreads();               // all samp reads done
  // E: sample v -> samp (overwrite)
  sample16(Xb, pws + 4 * 64, pas + 4 * 64, samp, pix, cg, p7);
  __syncthreads();
  // F: values GEMM -> vl regs
  float vl[16];
  gemm16s(&samp[pix * 64], vw + (size_t)cgu * 16 * 64, p7, vl);
  __syncthreads();               // all samp reads done
  // F2: commit ek -> ekt, vl -> samp (both ch-major, XOR-swizzled; same index)
#pragma unroll
  for (int j = 0; j < 16; j++) {
    int row = cg * 16 + j;
    int d = row * 64 + ((((pix >> 2) ^ (row & 7)) << 2) | (pix & 3));
    ekt[d]  = ek[j];
    samp[d] = vl[j];
  }
  __syncthreads();
  // G: per-wave (=per-head) context: lane owns 2x2 (k,v) block; den folded in
  {
    const int l = pix, h = cg;
    const int k2 = l >> 3, v2 = l & 7;
    const int hr0 = h * 16 + 2 * k2, hr1 = hr0 + 1;
    const int vv0 = h * 16 + 2 * v2, vv1 = vv0 + 1;
    float a00 = 0, a01 = 0, a10 = 0, a11 = 0, d0 = 0, d1 = 0;
#pragma unroll 4
    for (int p = 0; p < 16; p++) {
      float4 e0 = *(const float4*)&ekt[swq(hr0, p)];
      float4 e1 = *(const float4*)&ekt[swq(hr1, p)];
      float4 w0 = *(const float4*)&samp[swq(vv0, p)];
      float4 w1 = *(const float4*)&samp[swq(vv1, p)];
      a00 += e0.x * w0.x + e0.y * w0.y + e0.z * w0.z + e0.w * w0.w;
      a01 += e0.x * w1.x + e0.y * w1.y + e0.z * w1.z + e0.w * w1.w;
      a10 += e1.x * w0.x + e1.y * w0.y + e1.z * w0.z + e1.w * w0.w;
      a11 += e1.x * w1.x + e1.y * w1.y + e1.z * w1.z + e1.w * w1.w;
      d0 += e0.x + e0.y + e0.z + e0.w;
      d1 += e1.x + e1.y + e1.z + e1.w;
    }
    float* nb = num + n * 1024 + h * 256;
    atomicAdd(&nb[(2 * k2 + 0) * 16 + 2 * v2 + 0], a00);
    atomicAdd(&nb[(2 * k2 + 0) * 16 + 2 * v2 + 1], a01);
    atomicAdd(&nb[(2 * k2 + 1) * 16 + 2 * v2 + 0], a10);
    atomicAdd(&nb[(2 * k2 + 1) * 16 + 2 * v2 + 1], a11);
    if (v2 == 0) {
      atomicAdd(&den[n * 64 + h * 16 + 2 * k2 + 0], d0);
      atomicAdd(&den[n * 64 + h * 16 + 2 * k2 + 1], d1);
    }
  }
}

// ---------------- K3: query path + output (22KB LDS, softmax+attended in regs) ----------------
__global__ __launch_bounds__(256, 6) void k_output(
    const float* __restrict__ x,
    const float* __restrict__ qow, const float* __restrict__ qob,
    const float* __restrict__ qw,
    const float* __restrict__ rw, const float* __restrict__ rb,
    const float* __restrict__ num, const float* __restrict__ den,
    float* __restrict__ out) {
  __shared__ float samp[4096];   // sampled q (pix-major swz), later attended tile
  __shared__ float ctxs[1024];   // normalized context
  __shared__ float scr[512];     // red2 rows 0..7; then pws2 rows 0..3 / pas2 rows 4..7
  float* pws2 = scr;
  int*   pas2 = (int*)(scr + 256);

  const int t = threadIdx.x;
  const int bp = ((blockIdx.x & 7) << 9) | (blockIdx.x >> 3);
  const int xt = bp & 3, yrow = (bp >> 2) & 255, n = bp >> 10;
  const int xb = xt * 64;
  const int s0 = yrow * WW + xb;
  const float* xn = x + (size_t)n * CI * SS;
  const int pix = t & 63;
  const int cg = t >> 6;
  const int cgu = __builtin_amdgcn_readfirstlane(cg);
  const int p7 = pix & 7;
  const float* Xb = xn + (size_t)(cgu * 16) * SS;

  // ctx normalize (read in D; ordered by first barrier)
#pragma unroll
  for (int i = 0; i < 4; i++) {
    int e = t + i * 256;
    ctxs[e] = num[n * 1024 + e] / den[n * 64 + (e >> 4)];
  }

  // A: q offset partial dots -> scr rows {cg, 4+cg} (column-private)
  {
    const float* xc = Xb + s0 + pix;
    float p0 = 0, p1 = 0;
#pragma unroll 8
    for (int i = 0; i < 16; i++) {
      float xv = xc[(size_t)i * SS];
      p0 += qow[cgu * 16 + i] * xv;
      p1 += qow[64 + cgu * 16 + i] * xv;
    }
    scr[cg * 64 + pix] = p0;
    scr[(4 + cg) * 64 + pix] = p1;
  }
  __syncthreads();
  // A2: bilinear params; scr reads/writes column-private -> safe aliasing
  if (t < 64) {
    float oy = scr[0 * 64 + t] + scr[1 * 64 + t] + scr[2 * 64 + t] + scr[3 * 64 + t];
    float ox = scr[4 * 64 + t] + scr[5 * 64 + t] + scr[6 * 64 + t] + scr[7 * 64 + t];
    float py = (float)yrow + oy + qob[0];
    float px = (float)(xb + t) + ox + qob[1];
    float w4[4]; int a4[4];
    bilin_params(py, px, w4, a4);
#pragma unroll
    for (int q = 0; q < 4; q++) { pws2[q * 64 + t] = w4[q]; pas2[q * 64 + t] = a4[q]; }
  }
  __syncthreads();
  // C: sample q -> samp
  sample16(Xb, pws2, pas2, samp, pix, cg, p7);
  __syncthreads();
  // D: queries GEMM -> regs; per-head softmax in regs; attended via ctxs broadcast
  float at[16];
  {
    float qv[16];
    gemm16s(&samp[pix * 64], qw + (size_t)cgu * 16 * 64, p7, qv);
    float m = qv[0];
#pragma unroll
    for (int k = 1; k < 16; k++) m = fmaxf(m, qv[k]);
    float ssum = 0.f;
#pragma unroll
    for (int k = 0; k < 16; k++) { qv[k] = __expf(qv[k] - m); ssum += qv[k]; }
    float inv = 1.f / ssum;
#pragma unroll
    for (int j = 0; j < 16; j++) at[j] = 0.f;
    const float* cb = ctxs + cg * 256;
#pragma unroll 4
    for (int k = 0; k < 16; k++) {
      float qs = qv[k] * inv;
#pragma unroll
      for (int j = 0; j < 16; j++) at[j] += cb[k * 16 + j] * qs;
    }
  }
  __syncthreads();               // all samp reads done
  // E2: attended -> samp (pix-major swz)
#pragma unroll
  for (int mc = 0; mc < 4; mc++) {
    *reinterpret_cast<float4*>(&samp[swq(pix, cg * 4 + mc)]) =
        make_float4(at[mc * 4], at[mc * 4 + 1], at[mc * 4 + 2], at[mc * 4 + 3]);
  }
  __syncthreads();
  // F: output GEMM + bias, store
  {
    float a[16];
    gemm16s(&samp[pix * 64], rw + (size_t)cgu * 16 * 64, p7, a);
#pragma unroll
    for (int j = 0; j < 16; j++) {
      int o = cgu * 16 + j;
      out[(size_t)(n * 64 + o) * SS + s0 + pix] = a[j] + rb[o];
    }
  }
}

extern "C" void kernel_launch(void* const* d_in, const int* in_sizes, int n_in,
                              void* d_out, int out_size, void* d_ws, size_t ws_size,
                              hipStream_t stream) {
  const float* x   = (const float*)d_in[0];
  const float* kow = (const float*)d_in[1];
  const float* kob = (const float*)d_in[2];
  const float* kw  = (const float*)d_in[3];
  const float* qow = (const float*)d_in[4];
  const float* qob = (const float*)d_in[5];
  const float* qw  = (const float*)d_in[6];
  const float* vow = (const float*)d_in[7];
  const float* vob = (const float*)d_in[8];
  const float* vw  = (const float*)d_in[9];
  const float* rw  = (const float*)d_in[10];
  const float* rb  = (const float*)d_in[11];
  float* out = (float*)d_out;
  float* wsf = (float*)d_ws;
  float* num = wsf;          // 4096
  float* den = wsf + 4096;   // 256

  hipLaunchKernelGGL(k_zero, dim3(17), dim3(256), 0, stream, wsf);
  hipLaunchKernelGGL(k_context, dim3(4096), dim3(256), 0, stream,
                     x, kow, kob, kw, vow, vob, vw, num, den);
  hipLaunchKernelGGL(k_output, dim3(4096), dim3(256), 0, stream,
                     x, qow, qob, qw, rw, rb, num, den, out);
}

// Round 5
// 295.797 us; speedup vs baseline: 5.3778x; 1.5197x over previous
//
#include <hip/hip_runtime.h>
#include <math.h>

#define CI 64
#define HH 256
#define WW 256
#define SS (HH*WW)

typedef __attribute__((ext_vector_type(8))) short bf16x8;
typedef __attribute__((ext_vector_type(4))) float f32x4;

// workspace: num [N][1024] (h*256+k*16+v) -> 4096 ; den [N][64] -> 256
__global__ void k_zero(float* __restrict__ ws) {
  int i = blockIdx.x * 256 + threadIdx.x;
  if (i < 4352) ws[i] = 0.f;
}

__device__ __forceinline__ ushort f2bf(float f) {
  unsigned u = __float_as_uint(f);
  u += 0x7FFF + ((u >> 16) & 1);          // round-to-nearest-even
  return (ushort)(u >> 16);
}
__device__ __forceinline__ float bf2f(ushort h) { return __uint_as_float(((unsigned)h) << 16); }
__device__ __forceinline__ void split(float x, ushort& h, ushort& l) {
  h = f2bf(x); l = f2bf(x - bf2f(h));
}

// swizzled tiles: 64 rows x 64 ushort cols; chunk (8 elems) index XOR'd with row&7
__device__ __forceinline__ bf16x8 ld8(const ushort* t, int row, int c8) {
  return *reinterpret_cast<const bf16x8*>(t + row * 64 + ((c8 ^ (row & 7)) << 3));
}
__device__ __forceinline__ int swi(int row, int col) {   // scalar element index
  return row * 64 + ((((col >> 3) ^ (row & 7)) << 3) | (col & 7));
}

union B8 { bf16x8 v; ushort u[8]; };

// per-wave A-fragments of a 64x64 row-major weight matrix, rows h16..h16+15, hi/lo split
struct WFrag { bf16x8 h[2]; bf16x8 l[2]; };
__device__ __forceinline__ WFrag load_w(const float* __restrict__ W, int h16, int lane) {
  WFrag f;
  int m = lane & 15, q = lane >> 4;
#pragma unroll
  for (int ks = 0; ks < 2; ks++) {
    const float* p = W + (size_t)(h16 + m) * 64 + ks * 32 + q * 8;
    float4 f0 = *(const float4*)p, f1 = *(const float4*)(p + 4);
    float vals[8] = {f0.x, f0.y, f0.z, f0.w, f1.x, f1.y, f1.z, f1.w};
    B8 hh, ll;
#pragma unroll
    for (int j = 0; j < 8; j++) { ushort a, b; split(vals[j], a, b); hh.u[j] = a; ll.u[j] = b; }
    f.h[ks] = hh.v; f.l[ks] = ll.v;
  }
  return f;
}

// wave GEMM: D[16 rows][64 px] += W(h16 rows) * T, T px-row-major tile (rows=px, cols=c)
__device__ __forceinline__ void gemm_wave(const WFrag& w, const ushort* Th, const ushort* Tl,
                                          int lane, f32x4 acc[4]) {
  int m = lane & 15, q = lane >> 4;
#pragma unroll
  for (int nt = 0; nt < 4; nt++) {
#pragma unroll
    for (int ks = 0; ks < 2; ks++) {
      bf16x8 bh = ld8(Th, nt * 16 + m, ks * 4 + q);
      bf16x8 bl = ld8(Tl, nt * 16 + m, ks * 4 + q);
      acc[nt] = __builtin_amdgcn_mfma_f32_16x16x32_bf16(w.h[ks], bh, acc[nt], 0, 0, 0);
      acc[nt] = __builtin_amdgcn_mfma_f32_16x16x32_bf16(w.h[ks], bl, acc[nt], 0, 0, 0);
      acc[nt] = __builtin_amdgcn_mfma_f32_16x16x32_bf16(w.l[ks], bh, acc[nt], 0, 0, 0);
    }
  }
}

__device__ __forceinline__ void bilin_params(float py, float px, float w[4], int a[4]) {
  float y0f = floorf(py), x0f = floorf(px);
  float wy1 = py - y0f, wy0 = 1.f - wy1;
  float wx1 = px - x0f, wx0 = 1.f - wx1;
  int iy0 = (int)y0f, ix0 = (int)x0f;
  int iy1 = iy0 + 1, ix1 = ix0 + 1;
  float vy0 = (iy0 >= 0 && iy0 < HH) ? 1.f : 0.f;
  float vy1 = (iy1 >= 0 && iy1 < HH) ? 1.f : 0.f;
  float vx0 = (ix0 >= 0 && ix0 < WW) ? 1.f : 0.f;
  float vx1 = (ix1 >= 0 && ix1 < WW) ? 1.f : 0.f;
  int cy0 = min(max(iy0, 0), HH - 1), cy1 = min(max(iy1, 0), HH - 1);
  int cx0 = min(max(ix0, 0), WW - 1), cx1 = min(max(ix1, 0), WW - 1);
  w[0] = wy0 * wx0 * vy0 * vx0;
  w[1] = wy0 * wx1 * vy0 * vx1;
  w[2] = wy1 * wx0 * vy1 * vx0;
  w[3] = wy1 * wx1 * vy1 * vx1;
  a[0] = cy0 * WW + cx0;  a[1] = cy0 * WW + cx1;
  a[2] = cy1 * WW + cx0;  a[3] = cy1 * WW + cx1;
}

// sample 16 channels (this wave's block) of pixel `pix`, write bf16 hi/lo to px-row tile
__device__ __forceinline__ void sample16(const float* __restrict__ Xb,
                                         const float* __restrict__ pw,
                                         const int* __restrict__ pa,
                                         ushort* __restrict__ Sh, ushort* __restrict__ Sl,
                                         int pix, int cg) {
  float w0 = pw[0 * 64 + pix], w1 = pw[1 * 64 + pix], w2 = pw[2 * 64 + pix], w3 = pw[3 * 64 + pix];
  int a0 = pa[0 * 64 + pix], a1 = pa[1 * 64 + pix], a2 = pa[2 * 64 + pix], a3 = pa[3 * 64 + pix];
#pragma unroll 2
  for (int half = 0; half < 2; half++) {
    B8 hh, ll;
#pragma unroll
    for (int j = 0; j < 8; j++) {
      const float* Xc = Xb + (size_t)(half * 8 + j) * SS;
      float v = w0 * Xc[a0] + w1 * Xc[a1] + w2 * Xc[a2] + w3 * Xc[a3];
      ushort a, b; split(v, a, b); hh.u[j] = a; ll.u[j] = b;
    }
    int idx = pix * 64 + ((((cg * 2 + half) ^ (pix & 7))) << 3);
    *reinterpret_cast<bf16x8*>(Sh + idx) = hh.v;
    *reinterpret_cast<bf16x8*>(Sl + idx) = ll.v;
  }
}

// ---------------- K1: context accumulation ----------------
__global__ __launch_bounds__(256, 4) void k_context(
    const float* __restrict__ x,
    const float* __restrict__ kow, const float* __restrict__ kob,
    const float* __restrict__ kw,
    const float* __restrict__ vow, const float* __restrict__ vob,
    const float* __restrict__ vw,
    float* __restrict__ num, float* __restrict__ den) {
  __shared__ ushort Sh[4096], Sl[4096];   // sample tile (px-rows); later E tiles (chan-rows)
  __shared__ ushort Vh[4096], Vl[4096];   // V tiles (chan-rows); early alias: red/pws/pas
  float* red = (float*)Vh;                // [4][4][64] = 1024 f (4KB of Vh's 8KB)
  float* pws = (float*)Vl;                // [2][4][64] = 512 f
  int*   pas = (int*)Vl + 512;            // [2][4][64] = 512 i

  const int t = threadIdx.x;
  const int bp = ((blockIdx.x & 7) << 9) | (blockIdx.x >> 3);
  const int xt = bp & 3, yrow = (bp >> 2) & 255, n = bp >> 10;
  const int xb = xt * 64;
  const int s0 = yrow * WW + xb;
  const float* xn = x + (size_t)n * CI * SS;
  const int pix = t & 63;                 // lane
  const int cg = t >> 6;                  // wave = head
  const int cgu = __builtin_amdgcn_readfirstlane(cg);
  const int m = pix & 15, q = pix >> 4;
  const float* Xb = xn + (size_t)(cgu * 16) * SS;

  // A: offset partial dots (k and v)
  {
    const float* xc = Xb + s0 + pix;
    float p0 = 0, p1 = 0, p2 = 0, p3 = 0;
#pragma unroll 8
    for (int i = 0; i < 16; i++) {
      float xv = xc[(size_t)i * SS];
      p0 += kow[cgu * 16 + i] * xv;
      p1 += kow[64 + cgu * 16 + i] * xv;
      p2 += vow[cgu * 16 + i] * xv;
      p3 += vow[64 + cgu * 16 + i] * xv;
    }
    red[(0 * 4 + cg) * 64 + pix] = p0;
    red[(1 * 4 + cg) * 64 + pix] = p1;
    red[(2 * 4 + cg) * 64 + pix] = p2;
    red[(3 * 4 + cg) * 64 + pix] = p3;
  }
  __syncthreads();
  // A2: bilinear params (sel 0=k, 1=v)
  if (t < 128) {
    int p = t & 63, sel = t >> 6, qb = sel * 2;
    float oy = red[((qb + 0) * 4 + 0) * 64 + p] + red[((qb + 0) * 4 + 1) * 64 + p] +
               red[((qb + 0) * 4 + 2) * 64 + p] + red[((qb + 0) * 4 + 3) * 64 + p];
    float ox = red[((qb + 1) * 4 + 0) * 64 + p] + red[((qb + 1) * 4 + 1) * 64 + p] +
               red[((qb + 1) * 4 + 2) * 64 + p] + red[((qb + 1) * 4 + 3) * 64 + p];
    const float* ob = sel ? vob : kob;
    float py = (float)yrow + oy + ob[0];
    float px = (float)(xb + p) + ox + ob[1];
    float w4[4]; int a4[4];
    bilin_params(py, px, w4, a4);
#pragma unroll
    for (int qq = 0; qq < 4; qq++) { pws[(sel * 4 + qq) * 64 + p] = w4[qq]; pas[(sel * 4 + qq) * 64 + p] = a4[qq]; }
  }
  __syncthreads();
  // C: sample k -> S
  sample16(Xb, pws, pas, Sh, Sl, pix, cg);
  WFrag wk = load_w(kw, cgu * 16, pix);
  __syncthreads();
  // D: keys GEMM (MFMA) -> exp -> den
  float ek[16];
  {
    f32x4 acc[4] = {{0,0,0,0},{0,0,0,0},{0,0,0,0},{0,0,0,0}};
    gemm_wave(wk, Sh, Sl, pix, acc);
#pragma unroll
    for (int nt = 0; nt < 4; nt++)
#pragma unroll
      for (int r = 0; r < 4; r++) ek[nt * 4 + r] = __expf(acc[nt][r]);
    float s[4];
#pragma unroll
    for (int r = 0; r < 4; r++) s[r] = ek[r] + ek[4 + r] + ek[8 + r] + ek[12 + r];
#pragma unroll
    for (int mask = 1; mask < 16; mask <<= 1)
#pragma unroll
      for (int r = 0; r < 4; r++) s[r] += __shfl_xor(s[r], mask);
    if (m == 0) {
#pragma unroll
      for (int r = 0; r < 4; r++) atomicAdd(&den[n * 64 + cgu * 16 + q * 4 + r], s[r]);
    }
  }
  __syncthreads();   // all S reads done
  // E: sample v -> S (overwrite)
  sample16(Xb, pws + 4 * 64, pas + 4 * 64, Sh, Sl, pix, cg);
  WFrag wv = load_w(vw, cgu * 16, pix);
  __syncthreads();
  // F: values GEMM (MFMA)
  f32x4 vacc[4] = {{0,0,0,0},{0,0,0,0},{0,0,0,0},{0,0,0,0}};
  gemm_wave(wv, Sh, Sl, pix, vacc);
  __syncthreads();   // S reads done; red/pws/pas dead
  // F2: commit E -> S-area, V -> V-area (chan-row tiles, hi/lo)
#pragma unroll
  for (int nt = 0; nt < 4; nt++) {
    int px = nt * 16 + m;
#pragma unroll
    for (int r = 0; r < 4; r++) {
      int row = cgu * 16 + q * 4 + r;
      int ix = swi(row, px);
      ushort a, b;
      split(ek[nt * 4 + r], a, b);  Sh[ix] = a; Sl[ix] = b;
      split(vacc[nt][r], a, b);     Vh[ix] = a; Vl[ix] = b;
    }
  }
  __syncthreads();
  // G: ctx = E * V^T per head via MFMA (A=E chan-rows, B=V chan-rows; k = px)
  {
    f32x4 c = {0, 0, 0, 0};
#pragma unroll
    for (int ks = 0; ks < 2; ks++) {
      bf16x8 ah = ld8(Sh, cgu * 16 + m, ks * 4 + q);
      bf16x8 al = ld8(Sl, cgu * 16 + m, ks * 4 + q);
      bf16x8 bh = ld8(Vh, cgu * 16 + m, ks * 4 + q);
      bf16x8 bl = ld8(Vl, cgu * 16 + m, ks * 4 + q);
      c = __builtin_amdgcn_mfma_f32_16x16x32_bf16(ah, bh, c, 0, 0, 0);
      c = __builtin_amdgcn_mfma_f32_16x16x32_bf16(ah, bl, c, 0, 0, 0);
      c = __builtin_amdgcn_mfma_f32_16x16x32_bf16(al, bh, c, 0, 0, 0);
    }
    float* nb = num + n * 1024 + cgu * 256;
#pragma unroll
    for (int r = 0; r < 4; r++) atomicAdd(&nb[(q * 4 + r) * 16 + m], c[r]);
  }
}

// ---------------- K3: query path + output ----------------
__global__ __launch_bounds__(256, 4) void k_output(
    const float* __restrict__ x,
    const float* __restrict__ qow, const float* __restrict__ qob,
    const float* __restrict__ qw,
    const float* __restrict__ rw, const float* __restrict__ rb,
    const float* __restrict__ num, const float* __restrict__ den,
    float* __restrict__ out) {
  __shared__ ushort Sh[4096], Sl[4096];   // q-sample -> qsmT -> att (all px-row tiles)
  __shared__ float ctxs[1024];
  __shared__ float pws2[256];
  __shared__ int   pas2[256];
  float* red2 = (float*)Sh;               // [8][64] = 512 f, dead before C

  const int t = threadIdx.x;
  const int bp = ((blockIdx.x & 7) << 9) | (blockIdx.x >> 3);
  const int xt = bp & 3, yrow = (bp >> 2) & 255, n = bp >> 10;
  const int xb = xt * 64;
  const int s0 = yrow * WW + xb;
  const float* xn = x + (size_t)n * CI * SS;
  const int pix = t & 63;
  const int cg = t >> 6;
  const int cgu = __builtin_amdgcn_readfirstlane(cg);
  const int m = pix & 15, q = pix >> 4;
  const float* Xb = xn + (size_t)(cgu * 16) * SS;

  // ctx normalize (used in E; ordered by barriers)
#pragma unroll
  for (int i = 0; i < 4; i++) {
    int e = t + i * 256;
    ctxs[e] = num[n * 1024 + e] / den[n * 64 + (e >> 4)];
  }

  // A: q offset partial dots -> red2 (rows cg, 4+cg)
  {
    const float* xc = Xb + s0 + pix;
    float p0 = 0, p1 = 0;
#pragma unroll 8
    for (int i = 0; i < 16; i++) {
      float xv = xc[(size_t)i * SS];
      p0 += qow[cgu * 16 + i] * xv;
      p1 += qow[64 + cgu * 16 + i] * xv;
    }
    red2[cg * 64 + pix] = p0;
    red2[(4 + cg) * 64 + pix] = p1;
  }
  __syncthreads();
  // A2
  if (t < 64) {
    float oy = red2[0 * 64 + t] + red2[1 * 64 + t] + red2[2 * 64 + t] + red2[3 * 64 + t];
    float ox = red2[4 * 64 + t] + red2[5 * 64 + t] + red2[6 * 64 + t] + red2[7 * 64 + t];
    float py = (float)yrow + oy + qob[0];
    float px = (float)(xb + t) + ox + qob[1];
    float w4[4]; int a4[4];
    bilin_params(py, px, w4, a4);
#pragma unroll
    for (int qq = 0; qq < 4; qq++) { pws2[qq * 64 + t] = w4[qq]; pas2[qq * 64 + t] = a4[qq]; }
  }
  __syncthreads();
  // C: sample q -> S (overwrites red2)
  sample16(Xb, pws2, pas2, Sh, Sl, pix, cg);
  WFrag wq = load_w(qw, cgu * 16, pix);
  __syncthreads();
  // D: queries GEMM (MFMA) + per-(px,head) softmax over 16 channels, in regs
  float qsm[16];
  {
    f32x4 acc[4] = {{0,0,0,0},{0,0,0,0},{0,0,0,0},{0,0,0,0}};
    gemm_wave(wq, Sh, Sl, pix, acc);
#pragma unroll
    for (int nt = 0; nt < 4; nt++) {
      float mx = fmaxf(fmaxf(acc[nt][0], acc[nt][1]), fmaxf(acc[nt][2], acc[nt][3]));
      mx = fmaxf(mx, __shfl_xor(mx, 16));
      mx = fmaxf(mx, __shfl_xor(mx, 32));
      float e[4]; float ssum = 0.f;
#pragma unroll
      for (int r = 0; r < 4; r++) { e[r] = __expf(acc[nt][r] - mx); ssum += e[r]; }
      ssum += __shfl_xor(ssum, 16);
      ssum += __shfl_xor(ssum, 32);
      float inv = 1.f / ssum;
#pragma unroll
      for (int r = 0; r < 4; r++) qsm[nt * 4 + r] = e[r] * inv;
    }
  }
  __syncthreads();   // S reads done
  // D2: write qsm^T -> S (px-row tile, col = h*16 + kdim)
#pragma unroll
  for (int nt = 0; nt < 4; nt++) {
    int px = nt * 16 + m;
#pragma unroll
    for (int r = 0; r < 4; r++) {
      int ix = swi(px, cgu * 16 + q * 4 + r);
      ushort a, b; split(qsm[nt * 4 + r], a, b);
      Sh[ix] = a; Sl[ix] = b;
    }
  }
  __syncthreads();
  // E: attended = ctx^T (A, K-padded to 32) x qsm (B) per head
  f32x4 att[4];
  {
    bf16x8 ah, al;
    B8 hh, ll;
#pragma unroll
    for (int j = 0; j < 8; j++) {
      float cv = (q < 2) ? ctxs[cgu * 256 + (q * 8 + j) * 16 + m] : 0.f;
      ushort a, b; split(cv, a, b); hh.u[j] = a; ll.u[j] = b;
    }
    ah = hh.v; al = ll.v;
    bf16x8 z = {0, 0, 0, 0, 0, 0, 0, 0};
#pragma unroll
    for (int nt = 0; nt < 4; nt++) {
      bf16x8 bh = (q < 2) ? ld8(Sh, nt * 16 + m, cgu * 2 + q) : z;
      bf16x8 bl = (q < 2) ? ld8(Sl, nt * 16 + m, cgu * 2 + q) : z;
      f32x4 c = {0, 0, 0, 0};
      c = __builtin_amdgcn_mfma_f32_16x16x32_bf16(ah, bh, c, 0, 0, 0);
      c = __builtin_amdgcn_mfma_f32_16x16x32_bf16(ah, bl, c, 0, 0, 0);
      c = __builtin_amdgcn_mfma_f32_16x16x32_bf16(al, bh, c, 0, 0, 0);
      att[nt] = c;
    }
  }
  __syncthreads();   // S reads done
  // E2: write att -> S (px-row tile, col = h*16 + vdim)
#pragma unroll
  for (int nt = 0; nt < 4; nt++) {
    int px = nt * 16 + m;
#pragma unroll
    for (int r = 0; r < 4; r++) {
      int ix = swi(px, cgu * 16 + q * 4 + r);
      ushort a, b; split(att[nt][r], a, b);
      Sh[ix] = a; Sl[ix] = b;
    }
  }
  WFrag wr = load_w(rw, cgu * 16, pix);
  float rbv[4];
#pragma unroll
  for (int r = 0; r < 4; r++) rbv[r] = rb[cgu * 16 + q * 4 + r];
  __syncthreads();
  // F: output GEMM + bias, store
  {
    f32x4 oacc[4] = {{0,0,0,0},{0,0,0,0},{0,0,0,0},{0,0,0,0}};
    gemm_wave(wr, Sh, Sl, pix, oacc);
#pragma unroll
    for (int nt = 0; nt < 4; nt++) {
#pragma unroll
      for (int r = 0; r < 4; r++) {
        int o = cgu * 16 + q * 4 + r;
        out[(size_t)(n * 64 + o) * SS + s0 + nt * 16 + m] = oacc[nt][r] + rbv[r];
      }
    }
  }
}

extern "C" void kernel_launch(void* const* d_in, const int* in_sizes, int n_in,
                              void* d_out, int out_size, void* d_ws, size_t ws_size,
                              hipStream_t stream) {
  const float* x   = (const float*)d_in[0];
  const float* kow = (const float*)d_in[1];
  const float* kob = (const float*)d_in[2];
  const float* kw  = (const float*)d_in[3];
  const float* qow = (const float*)d_in[4];
  const float* qob = (const float*)d_in[5];
  const float* qw  = (const float*)d_in[6];
  const float* vow = (const float*)d_in[7];
  const float* vob = (const float*)d_in[8];
  const float* vw  = (const float*)d_in[9];
  const float* rw  = (const float*)d_in[10];
  const float* rb  = (const float*)d_in[11];
  float* out = (float*)d_out;
  float* wsf = (float*)d_ws;
  float* num = wsf;          // 4096
  float* den = wsf + 4096;   // 256

  hipLaunchKernelGGL(k_zero, dim3(17), dim3(256), 0, stream, wsf);
  hipLaunchKernelGGL(k_context, dim3(4096), dim3(256), 0, stream,
                     x, kow, kob, kw, vow, vob, vw, num, den);
  hipLaunchKernelGGL(k_output, dim3(4096), dim3(256), 0, stream,
                     x, qow, qob, qw, rw, rb, num, den, out);
}